// Round 1
// baseline (682.086 us; speedup 1.0000x reference)
//
#include <hip/hip_runtime.h>
#include <cstdint>
#include <cstddef>

#define CCH 128
#define BM 64
#define BN_EPS 1e-5f

// ---------------- rel-pos encoder: r[27][128] ----------------
__global__ void relpos_kernel(const float* __restrict__ pW1, const float* __restrict__ pb1,
                              const float* __restrict__ pW2, const float* __restrict__ pb2,
                              float* __restrict__ r) {
  int kv = blockIdx.x;   // 0..26
  int c  = threadIdx.x;  // 0..127
  float pz = 1.f - (float)(kv / 9);
  float py = 1.f - (float)((kv / 3) % 3);
  float px = 1.f - (float)(kv % 3);
  float acc = pb2[c];
#pragma unroll
  for (int j = 0; j < 3; ++j) {
    float h = px * pW1[j] + py * pW1[3 + j] + pz * pW1[6 + j] + pb1[j];
    h = fmaxf(h, 0.f);
    acc += h * pW2[j * CCH + c];
  }
  r[kv * CCH + c] = acc;
}

// ---------------- CSR build ----------------
__global__ void hist_kernel(const int* __restrict__ qi, int* __restrict__ counts, int M) {
  int i = blockIdx.x * blockDim.x + threadIdx.x;
  int stride = gridDim.x * blockDim.x;
  for (; i < M; i += stride) atomicAdd(&counts[qi[i]], 1);
}

__global__ __launch_bounds__(256) void scan_block(const int* __restrict__ counts,
                                                  int* __restrict__ offs,
                                                  int* __restrict__ bsum, int n) {
  __shared__ int s[256];
  int tid = threadIdx.x;
  int i = blockIdx.x * 256 + tid;
  int v = (i < n) ? counts[i] : 0;
  s[tid] = v;
  __syncthreads();
  for (int off = 1; off < 256; off <<= 1) {
    int t = (tid >= off) ? s[tid - off] : 0;
    __syncthreads();
    s[tid] += t;
    __syncthreads();
  }
  if (i < n) offs[i] = s[tid] - v;  // exclusive within block
  if (tid == 255) bsum[blockIdx.x] = s[255];
}

// single block: in-place exclusive scan of bsum[0..nb)
__global__ __launch_bounds__(256) void scan_partials(int* __restrict__ bsum, int nb) {
  __shared__ int s[256];
  __shared__ int carry_s;
  int tid = threadIdx.x;
  if (tid == 0) carry_s = 0;
  __syncthreads();
  for (int base = 0; base < nb; base += 256) {
    int i = base + tid;
    int v = (i < nb) ? bsum[i] : 0;
    s[tid] = v;
    __syncthreads();
    for (int off = 1; off < 256; off <<= 1) {
      int t = (tid >= off) ? s[tid - off] : 0;
      __syncthreads();
      s[tid] += t;
      __syncthreads();
    }
    int excl = s[tid] - v + carry_s;
    if (i < nb) bsum[i] = excl;
    int tot = s[255];
    __syncthreads();
    if (tid == 0) carry_s += tot;
    __syncthreads();
  }
}

__global__ void scan_fix(int* __restrict__ offs, const int* __restrict__ bsum,
                         int* __restrict__ cursor, int n) {
  int i = blockIdx.x * 256 + threadIdx.x;
  if (i < n) {
    int o = offs[i] + bsum[blockIdx.x];
    offs[i] = o;
    cursor[i] = o;
  }
}

// pack key (20 bits) | kernel (<<20)
__global__ void scatter_kernel(const int* __restrict__ qi, const int* __restrict__ ki,
                               const int* __restrict__ kni, int* __restrict__ cursor,
                               unsigned* __restrict__ pack, int M) {
  int i = blockIdx.x * blockDim.x + threadIdx.x;
  int stride = gridDim.x * blockDim.x;
  for (; i < M; i += stride) {
    int q = qi[i];
    int p = atomicAdd(&cursor[q], 1);
    pack[p] = (unsigned)ki[i] | ((unsigned)kni[i] << 20);
  }
}

// ---------------- fp32 GEMM: C[nrows,128] = A[nrows,128] @ W[128,128] (+bias) ----------------
__global__ __launch_bounds__(256) void gemm128(const float* __restrict__ A,
                                               const float* __restrict__ W,
                                               const float* __restrict__ bias,
                                               float* __restrict__ C, int nrows) {
  __shared__ float As[BM * 129];
  __shared__ float Ws[128 * 128];
  int tid = threadIdx.x;
  int row0 = blockIdx.x * BM;
  // stage W: 4096 float4, contiguous
#pragma unroll
  for (int i = 0; i < 16; ++i) {
    int idx = tid + i * 256;
    reinterpret_cast<float4*>(Ws)[idx] = reinterpret_cast<const float4*>(W)[idx];
  }
  // stage A: BM x 128 with pad 129 (scalar LDS writes; pad breaks bank aliasing)
#pragma unroll
  for (int i = 0; i < (BM * 32) / 256; ++i) {
    int idx = tid + i * 256;
    int rr = idx >> 5, cc = idx & 31;
    int gr = row0 + rr;
    float4 a = make_float4(0.f, 0.f, 0.f, 0.f);
    if (gr < nrows) a = reinterpret_cast<const float4*>(A)[(size_t)gr * 32 + cc];
    float* dst = &As[rr * 129 + cc * 4];
    dst[0] = a.x; dst[1] = a.y; dst[2] = a.z; dst[3] = a.w;
  }
  __syncthreads();
  int tr = tid >> 4, tc = tid & 15;
  int r4 = tr * 4, c8 = tc * 8;
  float acc[4][8];
#pragma unroll
  for (int j = 0; j < 4; ++j)
#pragma unroll
    for (int l = 0; l < 8; ++l) acc[j][l] = 0.f;

#pragma unroll 4
  for (int k = 0; k < 128; ++k) {
    float a[4];
#pragma unroll
    for (int j = 0; j < 4; ++j) a[j] = As[(r4 + j) * 129 + k];
    float4 w0 = *reinterpret_cast<const float4*>(&Ws[k * 128 + c8]);
    float4 w1 = *reinterpret_cast<const float4*>(&Ws[k * 128 + c8 + 4]);
    float w[8] = {w0.x, w0.y, w0.z, w0.w, w1.x, w1.y, w1.z, w1.w};
#pragma unroll
    for (int j = 0; j < 4; ++j)
#pragma unroll
      for (int l = 0; l < 8; ++l) acc[j][l] = fmaf(a[j], w[l], acc[j][l]);
  }
  float bb[8];
  if (bias != nullptr) {
    float4 b0 = *reinterpret_cast<const float4*>(&bias[c8]);
    float4 b1 = *reinterpret_cast<const float4*>(&bias[c8 + 4]);
    bb[0] = b0.x; bb[1] = b0.y; bb[2] = b0.z; bb[3] = b0.w;
    bb[4] = b1.x; bb[5] = b1.y; bb[6] = b1.z; bb[7] = b1.w;
  } else {
#pragma unroll
    for (int l = 0; l < 8; ++l) bb[l] = 0.f;
  }
#pragma unroll
  for (int j = 0; j < 4; ++j) {
    int gr = row0 + r4 + j;
    if (gr < nrows) {
      float4 o0 = make_float4(acc[j][0] + bb[0], acc[j][1] + bb[1], acc[j][2] + bb[2], acc[j][3] + bb[3]);
      float4 o1 = make_float4(acc[j][4] + bb[4], acc[j][5] + bb[5], acc[j][6] + bb[6], acc[j][7] + bb[7]);
      float4* dst = reinterpret_cast<float4*>(&C[(size_t)gr * 128 + c8]);
      dst[0] = o0; dst[1] = o1;
    }
  }
}

// ---------------- attention: one wave per query, online softmax in registers ----------------
__global__ __launch_bounds__(256) void attn_kernel(const float* __restrict__ q,
                                                   const float* __restrict__ k,
                                                   const float* __restrict__ v,
                                                   const float* __restrict__ r,
                                                   const int* __restrict__ offs,
                                                   const int* __restrict__ counts,
                                                   const unsigned* __restrict__ pack,
                                                   float* __restrict__ AT, int nrows) {
  __shared__ float rs[27 * CCH];
  for (int i = threadIdx.x; i < 27 * CCH; i += 256) rs[i] = r[i];
  __syncthreads();
  int wid = threadIdx.x >> 6, lane = threadIdx.x & 63;
  int n = blockIdx.x * 4 + wid;
  if (n >= nrows) return;
  int c0 = lane * 2;  // lane handles channels c0, c0+1; head = lane>>3 (8 lanes x 2ch = 16 = D)
  float2 qv = *reinterpret_cast<const float2*>(&q[(size_t)n * CCH + c0]);
  float m_run = -INFINITY, l_run = 0.f, o0 = 0.f, o1 = 0.f;
  int start = offs[n], cnt = counts[n];
  for (int e = 0; e < cnt; ++e) {
    unsigned p = pack[start + e];
    int ke = (int)(p & 0xFFFFFu);
    int kn = (int)(p >> 20);
    float2 kv2 = *reinterpret_cast<const float2*>(&k[(size_t)ke * CCH + c0]);
    float2 rv2 = *reinterpret_cast<const float2*>(&rs[kn * CCH + c0]);
    float2 vv2 = *reinterpret_cast<const float2*>(&v[(size_t)ke * CCH + c0]);
    float t = qv.x * (kv2.x + rv2.x) + qv.y * (kv2.y + rv2.y);
    t += __shfl_xor(t, 1);
    t += __shfl_xor(t, 2);
    t += __shfl_xor(t, 4);             // 8-lane (=16 channel) head reduction
    float logit = t * 0.25f;           // / sqrt(D=16)
    float nm = fmaxf(m_run, logit);
    float sc = __expf(m_run - nm);
    float pe = __expf(logit - nm);
    l_run = l_run * sc + pe;
    m_run = nm;
    o0 = o0 * sc + pe * vv2.x;
    o1 = o1 * sc + pe * vv2.y;
  }
  float inv = (l_run > 0.f) ? 1.f / l_run : 0.f;  // empty segment -> zeros (matches segment_sum)
  float2 out2 = make_float2(o0 * inv, o1 * inv);
  *reinterpret_cast<float2*>(&AT[(size_t)n * CCH + c0]) = out2;
}

// ---------------- BatchNorm stats: stats[0..127]=sum, [128..255]=sumsq ----------------
__global__ __launch_bounds__(256) void bn_stats(const float* __restrict__ X, int nrows,
                                                float* __restrict__ stats) {
  __shared__ float s1[256], s2[256];
  int tid = threadIdx.x;
  int c = tid & 127, half = tid >> 7;
  float a = 0.f, b = 0.f;
  for (int row = blockIdx.x * 2 + half; row < nrows; row += gridDim.x * 2) {
    float vv = X[(size_t)row * CCH + c];
    a += vv;
    b += vv * vv;
  }
  s1[tid] = a; s2[tid] = b;
  __syncthreads();
  if (tid < 128) {
    atomicAdd(&stats[c], s1[tid] + s1[tid + 128]);
    atomicAdd(&stats[128 + c], s2[tid] + s2[tid + 128]);
  }
}

__device__ __forceinline__ float bn1c(float a, float sum, float sq, float g, float be, float invN) {
  float mean = sum * invN;
  float var = sq * invN - mean * mean;
  float rstd = rsqrtf(var + BN_EPS);
  return (a - mean) * rstd * g + be;
}

// out = bn(A)*g+be + X   (used for norm1+residual and norm2+residual)
__global__ void bn_apply_res(float* __restrict__ outp, const float* __restrict__ A,
                             const float* __restrict__ X, const float* __restrict__ stats,
                             const float* __restrict__ g, const float* __restrict__ be,
                             int n4, float invN) {
  int i = blockIdx.x * blockDim.x + threadIdx.x;
  int stride = gridDim.x * blockDim.x;
  for (; i < n4; i += stride) {
    int c4 = i & 31;
    float4 sm = reinterpret_cast<const float4*>(stats)[c4];
    float4 sq = reinterpret_cast<const float4*>(stats)[32 + c4];
    float4 gv = reinterpret_cast<const float4*>(g)[c4];
    float4 bv = reinterpret_cast<const float4*>(be)[c4];
    float4 av = reinterpret_cast<const float4*>(A)[i];
    float4 xv = reinterpret_cast<const float4*>(X)[i];
    float4 o;
    o.x = bn1c(av.x, sm.x, sq.x, gv.x, bv.x, invN) + xv.x;
    o.y = bn1c(av.y, sm.y, sq.y, gv.y, bv.y, invN) + xv.y;
    o.z = bn1c(av.z, sm.z, sq.z, gv.z, bv.z, invN) + xv.z;
    o.w = bn1c(av.w, sm.w, sq.w, gv.w, bv.w, invN) + xv.w;
    reinterpret_cast<float4*>(outp)[i] = o;
  }
}

// A = relu(bn(A)) in-place
__global__ void bn_relu_inplace(float* __restrict__ A, const float* __restrict__ stats,
                                const float* __restrict__ g, const float* __restrict__ be,
                                int n4, float invN) {
  int i = blockIdx.x * blockDim.x + threadIdx.x;
  int stride = gridDim.x * blockDim.x;
  for (; i < n4; i += stride) {
    int c4 = i & 31;
    float4 sm = reinterpret_cast<const float4*>(stats)[c4];
    float4 sq = reinterpret_cast<const float4*>(stats)[32 + c4];
    float4 gv = reinterpret_cast<const float4*>(g)[c4];
    float4 bv = reinterpret_cast<const float4*>(be)[c4];
    float4 av = reinterpret_cast<float4*>(A)[i];
    float4 o;
    o.x = fmaxf(bn1c(av.x, sm.x, sq.x, gv.x, bv.x, invN), 0.f);
    o.y = fmaxf(bn1c(av.y, sm.y, sq.y, gv.y, bv.y, invN), 0.f);
    o.z = fmaxf(bn1c(av.z, sm.z, sq.z, gv.z, bv.z, invN), 0.f);
    o.w = fmaxf(bn1c(av.w, sm.w, sq.w, gv.w, bv.w, invN), 0.f);
    reinterpret_cast<float4*>(A)[i] = o;
  }
}

static inline char* align_up(char* p, size_t a) {
  return (char*)(((uintptr_t)p + a - 1) & ~(uintptr_t)(a - 1));
}

extern "C" void kernel_launch(void* const* d_in, const int* in_sizes, int n_in,
                              void* d_out, int out_size, void* d_ws, size_t ws_size,
                              hipStream_t stream) {
  const float* x        = (const float*)d_in[0];
  const int*   key_idx  = (const int*)d_in[1];
  const int*   kern_idx = (const int*)d_in[2];
  const int*   qry_idx  = (const int*)d_in[3];
  const float* Wq = (const float*)d_in[4];  const float* bq = (const float*)d_in[5];
  const float* Wk = (const float*)d_in[6];  const float* bk = (const float*)d_in[7];
  const float* Wv = (const float*)d_in[8];  const float* bv = (const float*)d_in[9];
  const float* Wo = (const float*)d_in[10]; const float* bo = (const float*)d_in[11];
  const float* pW1 = (const float*)d_in[12]; const float* pb1 = (const float*)d_in[13];
  const float* pW2 = (const float*)d_in[14]; const float* pb2 = (const float*)d_in[15];
  const float* g1 = (const float*)d_in[16];  const float* be1 = (const float*)d_in[17];
  const float* mW1 = (const float*)d_in[18];
  const float* mg = (const float*)d_in[19];  const float* mb = (const float*)d_in[20];
  const float* mW2 = (const float*)d_in[21]; const float* mb2 = (const float*)d_in[22];
  const float* g2 = (const float*)d_in[23];  const float* be2 = (const float*)d_in[24];

  int N = in_sizes[0] / CCH;
  int M = in_sizes[1];

  char* p = (char*)d_ws;
  auto take = [&](size_t bytes) -> char* {
    char* q = align_up(p, 256);
    p = q + bytes;
    return q;
  };
  size_t NB = (size_t)N * CCH * sizeof(float);
  float* B0 = (float*)take(NB);          // q -> AO
  float* B1 = (float*)take(NB);          // k -> OUT_
  float* B2 = (float*)take(NB);          // v -> H1
  float* B3 = (float*)take(NB);          // AT -> H2
  float* rbuf = (float*)take(27 * CCH * sizeof(float));
  int* counts = (int*)take((size_t)N * sizeof(int));
  int* offs   = (int*)take((size_t)N * sizeof(int));
  int* cursor = (int*)take((size_t)N * sizeof(int));
  int* bsum   = (int*)take(4096);
  unsigned* pack = (unsigned*)take((size_t)M * sizeof(unsigned));
  float* stats = (float*)take(256 * sizeof(float));
  (void)ws_size; (void)n_in; (void)out_size;

  int nsb = (N + 255) / 256;
  int gblocks = (N + BM - 1) / BM;
  int n4 = N * 32;
  float invN = 1.f / (float)N;

  // CSR build
  hipMemsetAsync(counts, 0, (size_t)N * sizeof(int), stream);
  relpos_kernel<<<27, CCH, 0, stream>>>(pW1, pb1, pW2, pb2, rbuf);
  hist_kernel<<<1024, 256, 0, stream>>>(qry_idx, counts, M);
  scan_block<<<nsb, 256, 0, stream>>>(counts, offs, bsum, N);
  scan_partials<<<1, 256, 0, stream>>>(bsum, nsb);
  scan_fix<<<nsb, 256, 0, stream>>>(offs, bsum, cursor, N);
  scatter_kernel<<<1024, 256, 0, stream>>>(qry_idx, key_idx, kern_idx, cursor, pack, M);

  // projections
  gemm128<<<gblocks, 256, 0, stream>>>(x, Wq, bq, B0, N);
  gemm128<<<gblocks, 256, 0, stream>>>(x, Wk, bk, B1, N);
  gemm128<<<gblocks, 256, 0, stream>>>(x, Wv, bv, B2, N);

  // attention (one wave per query)
  attn_kernel<<<(N + 3) / 4, 256, 0, stream>>>(B0, B1, B2, rbuf, offs, counts, pack, B3, N);

  // output projection
  gemm128<<<gblocks, 256, 0, stream>>>(B3, Wo, bo, B0, N);

  // norm1 + residual
  hipMemsetAsync(stats, 0, 256 * sizeof(float), stream);
  bn_stats<<<256, 256, 0, stream>>>(B0, N, stats);
  bn_apply_res<<<2048, 256, 0, stream>>>(B1, B0, x, stats, g1, be1, n4, invN);

  // MLP
  gemm128<<<gblocks, 256, 0, stream>>>(B1, mW1, nullptr, B2, N);
  hipMemsetAsync(stats, 0, 256 * sizeof(float), stream);
  bn_stats<<<256, 256, 0, stream>>>(B2, N, stats);
  bn_relu_inplace<<<2048, 256, 0, stream>>>(B2, stats, mg, mb, n4, invN);
  gemm128<<<gblocks, 256, 0, stream>>>(B2, mW2, mb2, B3, N);

  // norm2 + residual
  hipMemsetAsync(stats, 0, 256 * sizeof(float), stream);
  bn_stats<<<256, 256, 0, stream>>>(B3, N, stats);
  bn_apply_res<<<2048, 256, 0, stream>>>((float*)d_out, B3, B1, stats, g2, be2, n4, invN);
}